// Round 1
// baseline (628.841 us; speedup 1.0000x reference)
//
#include <hip/hip_runtime.h>
#include <hip/hip_bf16.h>

typedef unsigned int u32;
typedef unsigned long long u64;

#define B 8
#define NANCH 100800
#define NCH 85
#define KPRE 1024
#define MAXDET 100
#define CONF 0.25f
#define IOU_T 0.45f
#define EPS_F 1e-7f
#define MAX_WH 7680.0f
#define CAP 4096

// ---------------- Kernel 1: per-anchor score + argmax (wave per anchor) ----------------
__global__ __launch_bounds__(256) void score_kernel(const float* __restrict__ pred,
                                                    u32* __restrict__ keys,
                                                    unsigned char* __restrict__ cls8) {
    const int total = B * NANCH;
    int gtid = blockIdx.x * blockDim.x + threadIdx.x;
    int wid = gtid >> 6;
    int lane = threadIdx.x & 63;
    int nwaves = (gridDim.x * blockDim.x) >> 6;

    for (int a = wid; a < total; a += nwaves) {
        const float* p = pred + (size_t)a * NCH;
        float c1 = p[4 + lane];                       // cols 4..67 (col4 = obj, cols 5..67 = classes 0..62)
        float c2 = (lane < 17) ? p[68 + lane] : 0.0f; // cols 68..84 = classes 63..79
        float obj = __shfl(c1, 0);

        float v1 = (lane >= 1) ? c1 * obj : -1.0f;
        int i1 = lane - 1;
        float v2 = (lane < 17) ? c2 * obj : -1.0f;
        int i2 = 63 + lane;

        float v; int c;
        if (v2 > v1) { v = v2; c = i2; } else { v = v1; c = i1; }

        #pragma unroll
        for (int m = 1; m < 64; m <<= 1) {
            float vo = __shfl_xor(v, m);
            int co = __shfl_xor(c, m);
            if (vo > v || (vo == v && co < c)) { v = vo; c = co; }
        }

        if (lane == 0) {
            bool valid = (obj > CONF) && (v > CONF);
            keys[a] = valid ? __float_as_uint(v) : 0u;
            cls8[a] = (unsigned char)c;
        }
    }
}

// ---------------- Kernel 2: per-batch exact top-1024 (hist narrow + bitonic) ----------------
__global__ __launch_bounds__(1024) void select_kernel(const float* __restrict__ pred,
                                                      const u32* __restrict__ keys,
                                                      const unsigned char* __restrict__ cls8,
                                                      float* __restrict__ sel_score,
                                                      float* __restrict__ sel_cls,
                                                      float* __restrict__ sel_box,
                                                      float* __restrict__ sel_obox,
                                                      float* __restrict__ sel_area) {
    #pragma clang fp contract(off)
    const int b = blockIdx.x;
    const int tid = threadIdx.x;
    const u32 BASE = 0x3E800000u; // bits of 0.25f

    __shared__ u32 hist[257];
    __shared__ int s_pivot;
    __shared__ int s_cnt;
    __shared__ u64 items[CAP];

    if (tid < 257) hist[tid] = 0;
    if (tid == 0) { s_cnt = 0; s_pivot = 0; }
    __syncthreads();

    const u32* kb = keys + (size_t)b * NANCH;
    for (int i = tid; i < NANCH; i += 1024) {
        u32 k = kb[i];
        if (k) {
            u32 bin = (k - BASE) >> 16;
            if (bin > 256) bin = 256;
            atomicAdd(&hist[bin], 1u);
        }
    }
    __syncthreads();

    if (tid == 0) {
        int cum = 0, piv = 0;
        for (int t = 256; t >= 0; --t) {
            cum += (int)hist[t];
            if (cum >= KPRE) { piv = t; break; }
        }
        s_pivot = piv;
    }
    __syncthreads();
    int piv = s_pivot;

    for (int i = tid; i < NANCH; i += 1024) {
        u32 k = kb[i];
        if (k) {
            u32 bin = (k - BASE) >> 16;
            if (bin > 256) bin = 256;
            if ((int)bin >= piv) {
                int pos = atomicAdd(&s_cnt, 1);
                if (pos < CAP) items[pos] = (((u64)(~k)) << 32) | (u32)i;
            }
        }
    }
    __syncthreads();

    int n = s_cnt; if (n > CAP) n = CAP;
    for (int i = tid; i < CAP; i += 1024)
        if (i >= n) items[i] = ~0ull;
    __syncthreads();

    // bitonic ascending sort of CAP u64 keys
    for (int k = 2; k <= CAP; k <<= 1) {
        for (int j = k >> 1; j >= 1; j >>= 1) {
            for (int p = tid; p < CAP / 2; p += 1024) {
                int i = ((p & ~(j - 1)) << 1) | (p & (j - 1));
                int partner = i | j;
                bool up = ((i & k) == 0);
                u64 a = items[i], c = items[partner];
                if ((a > c) == up) { items[i] = c; items[partner] = a; }
            }
            __syncthreads();
        }
    }

    // threads 0..1023 each finalize one slot
    if (tid < KPRE) {
        u64 it = items[tid];
        u32 invk = (u32)(it >> 32);
        int gi = b * KPRE + tid;
        if (invk != 0xFFFFFFFFu && tid < n) {
            u32 k = ~invk;
            u32 idx = (u32)it;
            float score = __uint_as_float(k);
            const float* pb = pred + ((size_t)b * NANCH + idx) * NCH;
            float cx = pb[0], cy = pb[1], w = pb[2], h = pb[3];
            float x1 = cx - w * 0.5f;
            float y1 = cy - h * 0.5f;
            float x2 = cx + w * 0.5f;
            float y2 = cy + h * 0.5f;
            float clsf = (float)cls8[(size_t)b * NANCH + idx];
            float off = clsf * MAX_WH;
            float bx1 = x1 + off, by1 = y1 + off, bx2 = x2 + off, by2 = y2 + off;
            float area = (bx2 - bx1) * (by2 - by1);
            sel_score[gi] = score;
            sel_cls[gi] = clsf;
            ((float4*)sel_box)[gi] = make_float4(x1, y1, x2, y2);
            ((float4*)sel_obox)[gi] = make_float4(bx1, by1, bx2, by2);
            sel_area[gi] = area;
        } else {
            sel_score[gi] = -1.0f;
            sel_cls[gi] = 0.0f;
            ((float4*)sel_box)[gi] = make_float4(0.f, 0.f, 0.f, 0.f);
            ((float4*)sel_obox)[gi] = make_float4(0.f, 0.f, 0.f, 0.f);
            sel_area[gi] = 0.0f;
        }
    }
}

// ---------------- Kernel 3: IOU bitmask (upper triangle), words >= row chunk ----------------
__global__ __launch_bounds__(256) void iou_kernel(const float* __restrict__ sel_obox,
                                                  const float* __restrict__ sel_area,
                                                  u64* __restrict__ mask) {
    #pragma clang fp contract(off)
    const int c = blockIdx.x;  // row chunk 0..15
    const int b = blockIdx.y;  // batch
    const int tid = threadIdx.x;
    const int base = c * 64;
    const int ncols = (16 - c) * 64;

    __shared__ float4 sbox[KPRE];
    __shared__ float sarea[KPRE];

    for (int e = tid; e < ncols; e += 256) {
        int j = base + e;
        sbox[e] = ((const float4*)sel_obox)[b * KPRE + j];
        sarea[e] = sel_area[b * KPRE + j];
    }
    __syncthreads();

    const int ntask = 64 * (16 - c);
    for (int task = tid; task < ntask; task += 256) {
        int row = base + (task & 63);
        int w = c + (task >> 6);
        float4 rb = sbox[row - base];
        float ra = sarea[row - base];
        u64 m = 0;
        #pragma unroll 4
        for (int j2 = 0; j2 < 64; ++j2) {
            int jg = w * 64 + j2;
            float4 cb = sbox[jg - base];
            float ca = sarea[jg - base];
            float ltx = fmaxf(rb.x, cb.x);
            float lty = fmaxf(rb.y, cb.y);
            float rbx = fminf(rb.z, cb.z);
            float rby = fminf(rb.w, cb.w);
            float iw = fmaxf(rbx - ltx, 0.0f);
            float ih = fmaxf(rby - lty, 0.0f);
            float inter = iw * ih;
            float uni = ra + ca - inter;
            float iou = inter / (uni + EPS_F);
            if ((iou > IOU_T) && (jg > row)) m |= (1ull << j2);
        }
        mask[((size_t)b * KPRE + row) * 16 + w] = m;
    }
}

// ---------------- Kernel 4: sequential greedy resolve + output ----------------
__global__ __launch_bounds__(64) void resolve_kernel(const u64* __restrict__ mask,
                                                     const float* __restrict__ sel_score,
                                                     const float* __restrict__ sel_cls,
                                                     const float* __restrict__ sel_box,
                                                     float* __restrict__ out) {
    const int b = blockIdx.x;
    const int lane = threadIdx.x;

    __shared__ u64 s_keptw[16];
    __shared__ int s_keep[128];
    __shared__ int s_nk;

    u64 rem = 0; // lane w (<16) owns removed-bits for word w
    for (int w = 0; w < 16; ++w) {
        float s = sel_score[b * KPRE + w * 64 + lane];
        u64 bal = __ballot(s <= 0.0f);
        if (lane == w) rem = bal;
    }

    for (int W = 0; W < 16; ++W) {
        u64 cur = (u64)__shfl((long long)rem, W);
        u64 diag = mask[((size_t)b * KPRE + W * 64 + lane) * 16 + W];
        u64 keptbits = 0;
        for (int t = 0; t < 64; ++t) {
            u64 dm = (u64)__shfl((long long)diag, t);
            if (!((cur >> t) & 1ull)) {
                keptbits |= (1ull << t);
                cur |= dm;
            }
        }
        if (lane == W) rem = cur;
        if (lane == 0) s_keptw[W] = keptbits;
        // propagate kept rows' suppression to future words
        for (int t = 0; t < 64; ++t) {
            u64 m = 0;
            if (lane < 16) m = mask[((size_t)b * KPRE + W * 64 + t) * 16 + lane];
            if (((keptbits >> t) & 1ull) && lane > W) rem |= m;
        }
    }
    __syncthreads();

    if (lane == 0) {
        int nk = 0;
        for (int W = 0; W < 16 && nk < MAXDET; ++W) {
            u64 kb = s_keptw[W];
            while (kb && nk < MAXDET) {
                int t = __builtin_ctzll(kb);
                kb &= kb - 1;
                s_keep[nk++] = W * 64 + t;
            }
        }
        s_nk = nk;
    }
    __syncthreads();
    int nk = s_nk;

    for (int r = lane; r < MAXDET; r += 64) {
        float o0 = 0, o1 = 0, o2 = 0, o3 = 0, o4 = 0, o5 = 0;
        if (r < nk) {
            int i = s_keep[r];
            int gi = b * KPRE + i;
            float4 bx = ((const float4*)sel_box)[gi];
            o0 = bx.x; o1 = bx.y; o2 = bx.z; o3 = bx.w;
            o4 = sel_score[gi];
            o5 = sel_cls[gi];
        }
        float* po = out + ((size_t)b * MAXDET + r) * 6;
        po[0] = o0; po[1] = o1; po[2] = o2; po[3] = o3; po[4] = o4; po[5] = o5;
    }
}

extern "C" void kernel_launch(void* const* d_in, const int* in_sizes, int n_in,
                              void* d_out, int out_size, void* d_ws, size_t ws_size,
                              hipStream_t stream) {
    const float* pred = (const float*)d_in[0];
    float* out = (float*)d_out;
    char* ws = (char*)d_ws;

    // workspace layout (bytes), all 16-aligned
    u32* keys            = (u32*)(ws + 0);              // 806400 * 4 = 3225600
    unsigned char* cls8  = (unsigned char*)(ws + 3225600); // 806400 -> ends 4032000
    float* sel_score     = (float*)(ws + 4032000);      // 8192*4 -> 4064768
    float* sel_cls       = (float*)(ws + 4064768);      // -> 4097536
    float* sel_box       = (float*)(ws + 4097536);      // 8192*16 -> 4228608
    float* sel_obox      = (float*)(ws + 4228608);      // -> 4359680
    float* sel_area      = (float*)(ws + 4359680);      // -> 4392448
    u64* mask            = (u64*)(ws + 4392448);        // 8*1024*16*8 -> 5441024

    score_kernel<<<4096, 256, 0, stream>>>(pred, keys, cls8);
    select_kernel<<<B, 1024, 0, stream>>>(pred, keys, cls8, sel_score, sel_cls,
                                          sel_box, sel_obox, sel_area);
    iou_kernel<<<dim3(16, B), 256, 0, stream>>>(sel_obox, sel_area, mask);
    resolve_kernel<<<B, 64, 0, stream>>>(mask, sel_score, sel_cls, sel_box, out);
}